// Round 19
// baseline (77.271 us; speedup 1.0000x reference)
//
#include <hip/hip_runtime.h>

// Problem constants: B=8, S=1024, E=128, H=32, DK=4.
constexpr int kS = 1024;

typedef __fp16 fp16x2 __attribute__((ext_vector_type(2)));
typedef _Float16 half4v __attribute__((ext_vector_type(4)));
typedef _Float16 half8v __attribute__((ext_vector_type(8)));
typedef float float4v __attribute__((ext_vector_type(4)));

// ---------------------------------------------------------------------------
// Feature-map attention (R14, verified): P[q,k] = e^{q.k/2}, q.k/2 in [-2,2].
// Deg-6 Chebyshev: e^s ~= sum_n b_n s^n (abs err ~4.5e-4) ->
// P = sum_a w_a m_q^a m_k^a over 210 monomials (|a|<=6, 4 vars).
//   M[a][c]  = sum_k m_k[a]*vv_k[c]   (vv = [z,1]; col 4 = denominator)
//   num[q][c] = sum_a m_q[a] * (w_a M[a][c]);  out = num[0..3]/num[4].
// R19: R18's featM v3 with the chunk-offset bug fixed (hb4 is uint4* = 2
// tokens/elem -> chunk base is ch<<6, not ch<<5; R18 paired chunk-1..3
// monomials with wrong V tokens -> absmax 0.27).
// ---------------------------------------------------------------------------

__device__ __forceinline__ float wcoef(int a0, int a1, int a2, int a3) {
  const float b[7] = {1.0000101f, 1.0010454f, 0.5001437f, 0.1641115f,
                      0.0413223f, 0.00972570f, 0.00156770f};
  const float f[7] = {1.f, 1.f, 2.f, 6.f, 24.f, 120.f, 720.f};
  const float p2[7] = {1.f, 2.f, 4.f, 8.f, 16.f, 32.f, 64.f};
  int n = a0 + a1 + a2 + a3;
  return b[n] * f[n] / (p2[n] * f[a0] * f[a1] * f[a2] * f[a3]);
}

// Canonical graded enumeration of the 210 monomials; all kernels share it.
template <class F>
__device__ __forceinline__ void for_each_mono(float z0, float z1, float z2,
                                              float z3, F&& f) {
  int idx = 0;
  float p0 = 1.f;
#pragma unroll
  for (int a0 = 0; a0 <= 6; ++a0) {
    float p1 = p0;
#pragma unroll
    for (int a1 = 0; a1 <= 6 - a0; ++a1) {
      float p2 = p1;
#pragma unroll
      for (int a2 = 0; a2 <= 6 - a0 - a1; ++a2) {
        float p3 = p2;
#pragma unroll
        for (int a3 = 0; a3 <= 6 - a0 - a1 - a2; ++a3) {
          f(idx, p3, a0, a1, a2, a3);
          ++idx;
          p3 *= z3;
        }
        p2 *= z2;
      }
      p1 *= z1;
    }
    p0 *= z0;
  }
}

// ---------------------------------------------------------------------------
// K1: quantum encoder (analytic collapse, verified R1-R17).
// ---------------------------------------------------------------------------
__global__ __launch_bounds__(256) void qenc_kernel(
    const float4* __restrict__ x4, const float* __restrict__ qp,
    uint2* __restrict__ h16u) {
  int idx = blockIdx.x * 256 + threadIdx.x;
  float4 a = x4[idx];
  float c0 = cosf(a.x + qp[0]);
  float c1 = cosf(a.y + qp[1]);
  float c2 = cosf(a.z + qp[2]);
  float c3 = cosf(a.w + qp[3]);
  float z1 = c0 * c1;
  float z2 = z1 * c2;
  float z3 = z2 * c3;
  float z0 = c1 * c2 * c3;
  union { half4v h; uint2 u; } z;
  z.h.x = (_Float16)z0;
  z.h.y = (_Float16)z1;
  z.h.z = (_Float16)z2;
  z.h.w = (_Float16)z3;
  int b = idx >> 15;
  int s = (idx >> 5) & (kS - 1);
  int head = idx & 31;
  int bh = b * 32 + head;
  h16u[(bh << 10) + s] = z.u;
}

// ---------------------------------------------------------------------------
// K2a v3 (fixed): M[bh][half][alpha][c] partials. Block = (bh, half of 512
// keys), 4 chunks of 128 keys. Phase1 (= verified v1): 2 threads/token write
// 105 monomials each into sm[mi][tok] (u16, lanes consecutive -> 2/bank,
// free). Phase2: thread alpha reads its row as 64 paired b32 (conflict-free)
// and V as 64 GLOBAL uniform uint4 (2 tokens each; base ch<<6 — R18 bugfix;
// 8KB/block, L1-hot, VMEM pipe -> zero LDS-pipe cost).
// ---------------------------------------------------------------------------
__global__ __launch_bounds__(256) void featM_kernel(
    const _Float16* __restrict__ h16, float* __restrict__ Mpart) {
  __shared__ ushort sm[210][134];  // 268B rows, 4B-aligned
  const int bh = blockIdx.x >> 1;
  const int half = blockIdx.x & 1;
  const int t = threadIdx.x;
  const bool hiH = t >= 128;
  const int tok = t & 127;
  const uint2* __restrict__ hb = (const uint2*)(h16) + (bh << 10) + (half << 9);
  const uint4* __restrict__ hb4 = (const uint4*)hb;

  float acc0 = 0.f, acc1 = 0.f, acc2 = 0.f, acc3 = 0.f, acc4 = 0.f;

  for (int ch = 0; ch < 4; ++ch) {
    // phase 1: monomials for this chunk's 128 tokens
    {
      union { uint2 u; half4v h; } uz;
      uz.u = hb[(ch << 7) + tok];
      float z0 = (float)uz.h.x, z1 = (float)uz.h.y;
      float z2 = (float)uz.h.z, z3 = (float)uz.h.w;
      for_each_mono(z0, z1, z2, z3,
                    [&](int mi, float m, int, int, int, int) {
                      if (hiH ? (mi >= 105) : (mi < 105)) {
                        union { _Float16 h; ushort u; } cv;
                        cv.h = (_Float16)m;
                        sm[mi][tok] = cv.u;
                      }
                    });
    }
    __syncthreads();
    // phase 2: M += (own-row m pairs) . (global V pairs)
    if (t < 210) {
      const uint* mrow = (const uint*)&sm[t][0];
      for (int k2 = 0; k2 < 64; ++k2) {
        union { uint u; fp16x2 f; } um;
        um.u = mrow[k2];
        float mA = (float)um.f.x;
        float mB = (float)um.f.y;
        union { uint4 u; half8v h; } vq;
        vq.u = hb4[(ch << 6) + k2];  // tokens 2*k2, 2*k2+1 (uniform, L1)
        acc0 += mA * (float)vq.h[0] + mB * (float)vq.h[4];
        acc1 += mA * (float)vq.h[1] + mB * (float)vq.h[5];
        acc2 += mA * (float)vq.h[2] + mB * (float)vq.h[6];
        acc3 += mA * (float)vq.h[3] + mB * (float)vq.h[7];
        acc4 += mA + mB;
      }
    }
    __syncthreads();
  }
  if (t < 210) {
    float* mp = Mpart + (((bh << 1) + half) * 210 + t) * 5;
    mp[0] = acc0; mp[1] = acc1; mp[2] = acc2; mp[3] = acc3; mp[4] = acc4;
  }
}

// ---------------------------------------------------------------------------
// K2b v5 (verbatim R17, passed): out_num[q] = m_q . Mw. Block = (bh, half);
// thread owns q and q+256. Mw rows packed f16x8 -> ONE uniform b128 per
// monomial. Inner a3-loop rolled for I-cache.
// ---------------------------------------------------------------------------
__global__ __launch_bounds__(256) void featC_kernel(
    const _Float16* __restrict__ h16, const float* __restrict__ Mpart,
    uint2* __restrict__ o16u2) {
  __shared__ uint4 Mwh[210];
  const int bh = blockIdx.x >> 1;
  const int qh = blockIdx.x & 1;
  const int t = threadIdx.x;

  if (t < 210) {
    float w = 0.f;
    for_each_mono(1.f, 1.f, 1.f, 1.f,
                  [&](int mi, float, int a0, int a1, int a2, int a3) {
                    if (mi == t) w = wcoef(a0, a1, a2, a3);
                  });
    const float* p0 = Mpart + ((bh << 1) * 210 + t) * 5;
    const float* p1 = p0 + 210 * 5;
    float c0 = w * (p0[0] + p1[0]);
    float c1 = w * (p0[1] + p1[1]);
    float c2 = w * (p0[2] + p1[2]);
    float c3 = w * (p0[3] + p1[3]);
    float c4 = w * (p0[4] + p1[4]);
    union { fp16x2 f; uint u; } u01, u23, u4z;
    u01.f = __builtin_amdgcn_cvt_pkrtz(c0, c1);
    u23.f = __builtin_amdgcn_cvt_pkrtz(c2, c3);
    u4z.f = __builtin_amdgcn_cvt_pkrtz(c4, 0.f);
    Mwh[t] = make_uint4(u01.u, u23.u, u4z.u, 0u);
  }
  __syncthreads();

  const int q0 = (qh << 9) + t;  // second row: q0 + 256
  const uint2* hz = (const uint2*)h16 + (bh << 10);
  union { uint2 u; half4v h; } ua, ub;
  ua.u = hz[q0];
  ub.u = hz[q0 + 256];
  float xa0 = (float)ua.h.x, xa1 = (float)ua.h.y;
  float xa2 = (float)ua.h.z, xa3 = (float)ua.h.w;
  float xb0 = (float)ub.h.x, xb1 = (float)ub.h.y;
  float xb2 = (float)ub.h.z, xb3 = (float)ub.h.w;

  float nA0 = 0.f, nA1 = 0.f, nA2 = 0.f, nA3 = 0.f, nA4 = 0.f;
  float nB0 = 0.f, nB1 = 0.f, nB2 = 0.f, nB3 = 0.f, nB4 = 0.f;

  int idx = 0;
  float pa0 = 1.f, pb0 = 1.f;
#pragma unroll
  for (int a0 = 0; a0 <= 6; ++a0) {
    float pa1 = pa0, pb1 = pb0;
#pragma unroll
    for (int a1 = 0; a1 <= 6 - a0; ++a1) {
      float pa2 = pa1, pb2 = pb1;
#pragma unroll
      for (int a2 = 0; a2 <= 6 - a0 - a1; ++a2) {
        float pa3 = pa2, pb3 = pb2;
        const int n3 = 6 - a0 - a1 - a2;
#pragma unroll 1
        for (int a3 = 0; a3 <= n3; ++a3) {
          union { uint4 u; half8v h; } M;
          M.u = Mwh[idx];
          float M0 = (float)M.h[0], M1 = (float)M.h[1], M2 = (float)M.h[2];
          float M3 = (float)M.h[3], M4 = (float)M.h[4];
          nA0 += pa3 * M0; nA1 += pa3 * M1; nA2 += pa3 * M2;
          nA3 += pa3 * M3; nA4 += pa3 * M4;
          nB0 += pb3 * M0; nB1 += pb3 * M1; nB2 += pb3 * M2;
          nB3 += pb3 * M3; nB4 += pb3 * M4;
          ++idx;
          pa3 *= xa3; pb3 *= xb3;
        }
        pa2 *= xa2; pb2 *= xb2;
      }
      pa1 *= xa1; pb1 *= xb1;
    }
    pa0 *= xa0; pb0 *= xb0;
  }

  const int b_ = bh >> 5, head = bh & 31;
  {
    float inv = 1.0f / nA4;
    union { fp16x2 p[2]; uint2 u; } res;
    res.p[0] = __builtin_amdgcn_cvt_pkrtz(nA0 * inv, nA1 * inv);
    res.p[1] = __builtin_amdgcn_cvt_pkrtz(nA2 * inv, nA3 * inv);
    o16u2[(((b_ << 10) + q0) << 5) + head] = res.u;
  }
  {
    float inv = 1.0f / nB4;
    union { fp16x2 p[2]; uint2 u; } res;
    res.p[0] = __builtin_amdgcn_cvt_pkrtz(nB0 * inv, nB1 * inv);
    res.p[1] = __builtin_amdgcn_cvt_pkrtz(nB2 * inv, nB3 * inv);
    o16u2[(((b_ << 10) + q0 + 256) << 5) + head] = res.u;
  }
}

// ---------------------------------------------------------------------------
// K0: pack W into B-fragment layout wtb[e>>3][col][e&7] (f16).
// ---------------------------------------------------------------------------
__global__ __launch_bounds__(256) void wtb_kernel(
    const float* __restrict__ W, _Float16* __restrict__ wtb) {
  int i = blockIdx.x * 256 + threadIdx.x;  // 16384
  int col = i >> 7, e = i & 127;
  wtb[((e >> 3) << 10) + (col << 3) + (e & 7)] = (_Float16)W[i];
}

// ---------------------------------------------------------------------------
// K3: combine GEMM out[8192][128] = o16 @ W^T via mfma_f32_16x16x32_f16.
// (verified R6-R17: ~3 us)
// ---------------------------------------------------------------------------
__global__ __launch_bounds__(256) void combine_kernel(
    const _Float16* __restrict__ o16, const _Float16* __restrict__ wtb,
    float* __restrict__ out) {
  const int lane = threadIdx.x & 63;
  const int wv = threadIdx.x >> 6;
  const int job = blockIdx.x * 4 + wv;  // 0..4095
  const int rt = job >> 3, ct = job & 7;
  const int c = lane & 15, g = lane >> 4;
  const uint4* a4 = (const uint4*)o16;
  const uint4* b4 = (const uint4*)wtb;
  const int arow = (rt << 4) + c;
  union U4H { uint4 u; half8v h; };
  float4v acc = {};
#pragma unroll
  for (int t = 0; t < 4; ++t) {
    U4H ua, ub;
    ua.u = a4[(arow << 4) + (t << 2) + g];
    ub.u = b4[(((t << 2) + g) << 7) + (ct << 4) + c];
    acc = __builtin_amdgcn_mfma_f32_16x16x32_f16(ua.h, ub.h, acc, 0, 0, 0);
  }
  const int orow = (rt << 4) + (g << 2);
  const int ocol = (ct << 4) + c;
#pragma unroll
  for (int reg = 0; reg < 4; ++reg)
    out[(orow + reg) * 128 + ocol] = acc[reg];
}

extern "C" void kernel_launch(void* const* d_in, const int* in_sizes, int n_in,
                              void* d_out, int out_size, void* d_ws,
                              size_t ws_size, hipStream_t stream) {
  const float* x = (const float*)d_in[0];   // [8,1024,128] f32
  const float* qp = (const float*)d_in[1];  // [1,4] f32
  const float* W = (const float*)d_in[2];   // [128,128] f32
  float* out = (float*)d_out;               // [8,1024,128] f32

  char* ws = (char*)d_ws;
  _Float16* h16 = (_Float16*)ws;                 // [256][1024][4] f16 = 2 MB
  float* Mpart = (float*)(ws + (2 << 20));       // [256][2][210][5] f32 ~2.1MB
  _Float16* o16 = (_Float16*)(ws + (6 << 20));   // [8192][128] f16 = 2 MB
  _Float16* wtb = (_Float16*)(ws + (8 << 20));   // [16][128][8] f16 = 32 KB

  wtb_kernel<<<64, 256, 0, stream>>>(W, wtb);
  qenc_kernel<<<1024, 256, 0, stream>>>((const float4*)x, qp, (uint2*)h16);
  featM_kernel<<<512, 256, 0, stream>>>(h16, Mpart);
  featC_kernel<<<512, 256, 0, stream>>>(h16, Mpart, (uint2*)o16);
  combine_kernel<<<1024, 256, 0, stream>>>(o16, wtb, out);
}

// Round 20
// 60.515 us; speedup vs baseline: 1.2769x; 1.2769x over previous
//
#include <hip/hip_runtime.h>

// Problem constants: B=8, S=1024, E=128, H=32, DK=4.
constexpr int kS = 1024;

typedef __fp16 fp16x2 __attribute__((ext_vector_type(2)));
typedef _Float16 half4v __attribute__((ext_vector_type(4)));
typedef _Float16 half8v __attribute__((ext_vector_type(8)));
typedef float float4v __attribute__((ext_vector_type(4)));

// ---------------------------------------------------------------------------
// Feature-map attention (R14, verified): P[q,k] = e^{q.k/2}, q.k/2 in [-2,2].
// Deg-6 Chebyshev: e^s ~= sum_n b_n s^n (abs err ~4.5e-4) ->
// P = sum_a w_a m_q^a m_k^a over 210 monomials (|a|<=6, 4 vars).
//   M[a][c]  = sum_k m_k[a]*vv_k[c]   (vv = [z,1]; col 4 = denominator)
//   num[q][c] = sum_a m_q[a] * (w_a M[a][c]);  out = num[0..3]/num[4].
// R20: single-variable change vs R14 (53.6us verified): featM phase 2 reads
// monomials as PAIRED b32 (64 conflict-free reads, banks 3t+k2 mod 32) and
// vv as PACKED-f16 key-pairs (64 uniform b128). LDS-pipe/chunk/wave
// 2280 -> 1140 cyc. Everything else is R14 verbatim.
// ---------------------------------------------------------------------------

__device__ __forceinline__ float wcoef(int a0, int a1, int a2, int a3) {
  const float b[7] = {1.0000101f, 1.0010454f, 0.5001437f, 0.1641115f,
                      0.0413223f, 0.00972570f, 0.00156770f};
  const float f[7] = {1.f, 1.f, 2.f, 6.f, 24.f, 120.f, 720.f};
  const float p2[7] = {1.f, 2.f, 4.f, 8.f, 16.f, 32.f, 64.f};
  int n = a0 + a1 + a2 + a3;
  return b[n] * f[n] / (p2[n] * f[a0] * f[a1] * f[a2] * f[a3]);
}

// Canonical graded enumeration of the 210 monomials; all kernels share it.
template <class F>
__device__ __forceinline__ void for_each_mono(float z0, float z1, float z2,
                                              float z3, F&& f) {
  int idx = 0;
  float p0 = 1.f;
#pragma unroll
  for (int a0 = 0; a0 <= 6; ++a0) {
    float p1 = p0;
#pragma unroll
    for (int a1 = 0; a1 <= 6 - a0; ++a1) {
      float p2 = p1;
#pragma unroll
      for (int a2 = 0; a2 <= 6 - a0 - a1; ++a2) {
        float p3 = p2;
#pragma unroll
        for (int a3 = 0; a3 <= 6 - a0 - a1 - a2; ++a3) {
          f(idx, p3, a0, a1, a2, a3);
          ++idx;
          p3 *= z3;
        }
        p2 *= z2;
      }
      p1 *= z1;
    }
    p0 *= z0;
  }
}

// ---------------------------------------------------------------------------
// K1: quantum encoder (analytic collapse, verified R1-R19).
// ---------------------------------------------------------------------------
__global__ __launch_bounds__(256) void qenc_kernel(
    const float4* __restrict__ x4, const float* __restrict__ qp,
    uint2* __restrict__ h16u) {
  int idx = blockIdx.x * 256 + threadIdx.x;
  float4 a = x4[idx];
  float c0 = cosf(a.x + qp[0]);
  float c1 = cosf(a.y + qp[1]);
  float c2 = cosf(a.z + qp[2]);
  float c3 = cosf(a.w + qp[3]);
  float z1 = c0 * c1;
  float z2 = z1 * c2;
  float z3 = z2 * c3;
  float z0 = c1 * c2 * c3;
  union { half4v h; uint2 u; } z;
  z.h.x = (_Float16)z0;
  z.h.y = (_Float16)z1;
  z.h.z = (_Float16)z2;
  z.h.w = (_Float16)z3;
  int b = idx >> 15;
  int s = (idx >> 5) & (kS - 1);
  int head = idx & 31;
  int bh = b * 32 + head;
  h16u[(bh << 10) + s] = z.u;
}

// ---------------------------------------------------------------------------
// K2a v4: M[bh][half][alpha][c] partials. Block = (bh, half of 512 keys),
// 4 chunks of 128 keys.
// Phase1 (= verified R14): 2 threads/token write 105 monomials each into
// sm[mi][tok] (u16, lanes consecutive -> 2/bank, free). Lo-half threads also
// write vvp: packed-f16 key-pairs, vvp[kp] = {v0A,v0B,v1A,v1B,v2A,v2B,
// v3A,v3B} (4 u16 writes/thread, 2 lanes/word -> free).
// Phase2: thread alpha reads its row as 64 PAIRED b32 (banks (3t+k2)%32,
// gcd(3,32)=1 -> conflict-free) + 64 uniform b128 vv-pair reads.
// LDS ops/chunk/wave: 128 (was 256 in R14) -> ~1140 cyc (was 2280).
// ---------------------------------------------------------------------------
__global__ __launch_bounds__(256) void featM_kernel(
    const _Float16* __restrict__ h16, float* __restrict__ Mpart) {
  __shared__ ushort sm[210][134];  // 268B rows, 4B-aligned
  __shared__ uint4 vvp[64];        // packed f16 key-pairs for current chunk
  const int bh = blockIdx.x >> 1;
  const int half = blockIdx.x & 1;
  const int t = threadIdx.x;
  const bool hiH = t >= 128;
  const int tok = t & 127;
  const uint2* __restrict__ hb = (const uint2*)(h16) + (bh << 10) + (half << 9);

  float acc0 = 0.f, acc1 = 0.f, acc2 = 0.f, acc3 = 0.f, acc4 = 0.f;

  for (int ch = 0; ch < 4; ++ch) {
    // phase 1: monomials + packed vv for this chunk's 128 tokens
    {
      union { uint2 u; half4v h; ushort4 us; } uz;
      uz.u = hb[(ch << 7) + tok];
      float z0 = (float)uz.h.x, z1 = (float)uz.h.y;
      float z2 = (float)uz.h.z, z3 = (float)uz.h.w;
      if (!hiH) {
        // vvp[kp] ushort layout: [c*2 + ab] = v_c of key (2kp+ab)
        ushort* vw = (ushort*)vvp;
        int base = ((tok >> 1) << 3) + (tok & 1);
        vw[base + 0] = uz.us.x;
        vw[base + 2] = uz.us.y;
        vw[base + 4] = uz.us.z;
        vw[base + 6] = uz.us.w;
      }
      for_each_mono(z0, z1, z2, z3,
                    [&](int mi, float m, int, int, int, int) {
                      if (hiH ? (mi >= 105) : (mi < 105)) {
                        union { _Float16 h; ushort u; } cv;
                        cv.h = (_Float16)m;
                        sm[mi][tok] = cv.u;
                      }
                    });
    }
    __syncthreads();
    // phase 2: M += (own-row monomial pairs) . (packed vv pairs)
    if (t < 210) {
      const uint* mrow = (const uint*)&sm[t][0];
      for (int k2 = 0; k2 < 64; ++k2) {
        union { uint u; fp16x2 f; } um;
        um.u = mrow[k2];
        float mA = (float)um.f.x;
        float mB = (float)um.f.y;
        union { uint4 u; half8v h; } vq;
        vq.u = vvp[k2];  // uniform -> broadcast
        acc0 += mA * (float)vq.h[0] + mB * (float)vq.h[1];
        acc1 += mA * (float)vq.h[2] + mB * (float)vq.h[3];
        acc2 += mA * (float)vq.h[4] + mB * (float)vq.h[5];
        acc3 += mA * (float)vq.h[6] + mB * (float)vq.h[7];
        acc4 += mA + mB;
      }
    }
    __syncthreads();
  }
  if (t < 210) {
    float* mp = Mpart + (((bh << 1) + half) * 210 + t) * 5;
    mp[0] = acc0; mp[1] = acc1; mp[2] = acc2; mp[3] = acc3; mp[4] = acc4;
  }
}

// ---------------------------------------------------------------------------
// K2b (R14 v1 VERBATIM, verified 53.6us): out_num[q] = (w o m_q) . Mw.
// Block = (bh, q-chunk 256). Prologue reduces the 2 half-partials into LDS
// Mw[210][8] (b128-aligned, f32). Main loop: fully-unrolled 210-term
// contraction; w folds to compile-time literals.
// ---------------------------------------------------------------------------
__global__ __launch_bounds__(256) void featC_kernel(
    const _Float16* __restrict__ h16, const float* __restrict__ Mpart,
    uint2* __restrict__ o16u2) {
  __shared__ float Mw[210][8];
  const int bh = blockIdx.x >> 2;
  const int qc = blockIdx.x & 3;
  const int t = threadIdx.x;
  if (t < 210) {
    const float* m0 = Mpart + ((bh << 1) * 210 + t) * 5;
    const float* m1 = m0 + 210 * 5;
#pragma unroll
    for (int c = 0; c < 5; ++c) Mw[t][c] = m0[c] + m1[c];
  }
  __syncthreads();

  const int q = (qc << 8) + t;
  union { uint2 u; half4v h; } uz;
  uz.u = ((const uint2*)h16)[(bh << 10) + q];
  float z0 = (float)uz.h.x, z1 = (float)uz.h.y;
  float z2 = (float)uz.h.z, z3 = (float)uz.h.w;

  float n0 = 0.f, n1 = 0.f, n2 = 0.f, n3 = 0.f, den = 0.f;
  for_each_mono(z0, z1, z2, z3,
                [&](int mi, float m, int a0, int a1, int a2, int a3) {
                  float wm = m * wcoef(a0, a1, a2, a3);  // literal after unroll
                  float4 M4 = *(const float4*)&Mw[mi][0];
                  n0 += wm * M4.x; n1 += wm * M4.y;
                  n2 += wm * M4.z; n3 += wm * M4.w;
                  den += wm * Mw[mi][4];
                });

  float inv = 1.0f / den;
  union { fp16x2 p[2]; uint2 u; } res;
  res.p[0] = __builtin_amdgcn_cvt_pkrtz(n0 * inv, n1 * inv);
  res.p[1] = __builtin_amdgcn_cvt_pkrtz(n2 * inv, n3 * inv);
  int b = bh >> 5, head = bh & 31;
  o16u2[(((b << 10) + q) << 5) + head] = res.u;
}

// ---------------------------------------------------------------------------
// K0: pack W into B-fragment layout wtb[e>>3][col][e&7] (f16).
// ---------------------------------------------------------------------------
__global__ __launch_bounds__(256) void wtb_kernel(
    const float* __restrict__ W, _Float16* __restrict__ wtb) {
  int i = blockIdx.x * 256 + threadIdx.x;  // 16384
  int col = i >> 7, e = i & 127;
  wtb[((e >> 3) << 10) + (col << 3) + (e & 7)] = (_Float16)W[i];
}

// ---------------------------------------------------------------------------
// K3: combine GEMM out[8192][128] = o16 @ W^T via mfma_f32_16x16x32_f16.
// (verified R6-R19: ~3 us)
// ---------------------------------------------------------------------------
__global__ __launch_bounds__(256) void combine_kernel(
    const _Float16* __restrict__ o16, const _Float16* __restrict__ wtb,
    float* __restrict__ out) {
  const int lane = threadIdx.x & 63;
  const int wv = threadIdx.x >> 6;
  const int job = blockIdx.x * 4 + wv;  // 0..4095
  const int rt = job >> 3, ct = job & 7;
  const int c = lane & 15, g = lane >> 4;
  const uint4* a4 = (const uint4*)o16;
  const uint4* b4 = (const uint4*)wtb;
  const int arow = (rt << 4) + c;
  union U4H { uint4 u; half8v h; };
  float4v acc = {};
#pragma unroll
  for (int t = 0; t < 4; ++t) {
    U4H ua, ub;
    ua.u = a4[(arow << 4) + (t << 2) + g];
    ub.u = b4[(((t << 2) + g) << 7) + (ct << 4) + c];
    acc = __builtin_amdgcn_mfma_f32_16x16x32_f16(ua.h, ub.h, acc, 0, 0, 0);
  }
  const int orow = (rt << 4) + (g << 2);
  const int ocol = (ct << 4) + c;
#pragma unroll
  for (int reg = 0; reg < 4; ++reg)
    out[(orow + reg) * 128 + ocol] = acc[reg];
}

extern "C" void kernel_launch(void* const* d_in, const int* in_sizes, int n_in,
                              void* d_out, int out_size, void* d_ws,
                              size_t ws_size, hipStream_t stream) {
  const float* x = (const float*)d_in[0];   // [8,1024,128] f32
  const float* qp = (const float*)d_in[1];  // [1,4] f32
  const float* W = (const float*)d_in[2];   // [128,128] f32
  float* out = (float*)d_out;               // [8,1024,128] f32

  char* ws = (char*)d_ws;
  _Float16* h16 = (_Float16*)ws;                 // [256][1024][4] f16 = 2 MB
  float* Mpart = (float*)(ws + (2 << 20));       // [256][2][210][5] f32 ~2.1MB
  _Float16* o16 = (_Float16*)(ws + (6 << 20));   // [8192][128] f16 = 2 MB
  _Float16* wtb = (_Float16*)(ws + (8 << 20));   // [16][128][8] f16 = 32 KB

  wtb_kernel<<<64, 256, 0, stream>>>(W, wtb);
  qenc_kernel<<<1024, 256, 0, stream>>>((const float4*)x, qp, (uint2*)h16);
  featM_kernel<<<512, 256, 0, stream>>>(h16, Mpart);
  featC_kernel<<<1024, 256, 0, stream>>>(h16, Mpart, (uint2*)o16);
  combine_kernel<<<1024, 256, 0, stream>>>(o16, wtb, out);
}

// Round 21
// 44.476 us; speedup vs baseline: 1.7374x; 1.3606x over previous
//
#include <hip/hip_runtime.h>

// Problem constants: B=8, S=1024, E=128, H=32, DK=4.
constexpr int kS = 1024;

typedef __fp16 fp16x2 __attribute__((ext_vector_type(2)));
typedef _Float16 half4v __attribute__((ext_vector_type(4)));
typedef _Float16 half8v __attribute__((ext_vector_type(8)));
typedef float float4v __attribute__((ext_vector_type(4)));

// ---------------------------------------------------------------------------
// Feature-map attention (R14, verified): P[q,k] = e^{q.k/2}, q.k/2 in [-2,2].
// Deg-6 Chebyshev: e^s ~= sum_n b_n s^n (abs err ~4.5e-4) ->
// P = sum_a w_a m_q^a m_k^a over 210 monomials (|a|<=6, 4 vars).
//   M[a][c]  = sum_k m_k[a]*vv_k[c]   (vv = [z,1]; col 4 = denominator)
//   num[q][c] = sum_a m_q[a] * (w_a M[a][c]);  out = num[0..3]/num[4].
// R21: featM phase 2 -> MFMA, cloning combine_kernel's verified fragment
// pattern (A row-major b128 / B table [k>>3][col][k&7] / C row=(g<<2)+reg,
// col=c). LDS reads/wave/chunk: ~256 -> 20. Phase 1 (verified scatter)
// unchanged. All scalar-path phase-2 variants (R17/18/20) lost to v1 on
// cvt-unpack VALU cost; MFMA does the f16 contraction natively.
// ---------------------------------------------------------------------------

__device__ __forceinline__ float wcoef(int a0, int a1, int a2, int a3) {
  const float b[7] = {1.0000101f, 1.0010454f, 0.5001437f, 0.1641115f,
                      0.0413223f, 0.00972570f, 0.00156770f};
  const float f[7] = {1.f, 1.f, 2.f, 6.f, 24.f, 120.f, 720.f};
  const float p2[7] = {1.f, 2.f, 4.f, 8.f, 16.f, 32.f, 64.f};
  int n = a0 + a1 + a2 + a3;
  return b[n] * f[n] / (p2[n] * f[a0] * f[a1] * f[a2] * f[a3]);
}

// Canonical graded enumeration of the 210 monomials; all kernels share it.
template <class F>
__device__ __forceinline__ void for_each_mono(float z0, float z1, float z2,
                                              float z3, F&& f) {
  int idx = 0;
  float p0 = 1.f;
#pragma unroll
  for (int a0 = 0; a0 <= 6; ++a0) {
    float p1 = p0;
#pragma unroll
    for (int a1 = 0; a1 <= 6 - a0; ++a1) {
      float p2 = p1;
#pragma unroll
      for (int a2 = 0; a2 <= 6 - a0 - a1; ++a2) {
        float p3 = p2;
#pragma unroll
        for (int a3 = 0; a3 <= 6 - a0 - a1 - a2; ++a3) {
          f(idx, p3, a0, a1, a2, a3);
          ++idx;
          p3 *= z3;
        }
        p2 *= z2;
      }
      p1 *= z1;
    }
    p0 *= z0;
  }
}

// ---------------------------------------------------------------------------
// K1: quantum encoder (analytic collapse, verified R1-R20).
// ---------------------------------------------------------------------------
__global__ __launch_bounds__(256) void qenc_kernel(
    const float4* __restrict__ x4, const float* __restrict__ qp,
    uint2* __restrict__ h16u) {
  int idx = blockIdx.x * 256 + threadIdx.x;
  float4 a = x4[idx];
  float c0 = cosf(a.x + qp[0]);
  float c1 = cosf(a.y + qp[1]);
  float c2 = cosf(a.z + qp[2]);
  float c3 = cosf(a.w + qp[3]);
  float z1 = c0 * c1;
  float z2 = z1 * c2;
  float z3 = z2 * c3;
  float z0 = c1 * c2 * c3;
  union { half4v h; uint2 u; } z;
  z.h.x = (_Float16)z0;
  z.h.y = (_Float16)z1;
  z.h.z = (_Float16)z2;
  z.h.w = (_Float16)z3;
  int b = idx >> 15;
  int s = (idx >> 5) & (kS - 1);
  int head = idx & 31;
  int bh = b * 32 + head;
  h16u[(bh << 10) + s] = z.u;
}

// ---------------------------------------------------------------------------
// K2a v5 (MFMA phase 2): M[bh][half][row][c] = sum_k sm[row][k]*vvb[k][c].
// Block = (bh, half of 512 keys), 4 chunks of 128 keys.
// Phase1 (verified R14): 2 threads/token write 105 monomials each into
// sm[mi][tok] (u16, consecutive lanes -> 2/bank, free); lo threads also
// write vvb cols 0-3 for their key.
// Phase2 (NEW): mfma_f32_16x16x32_f16, combine-pattern fragments.
//   A: sm rows (stride 136 u16 = 17 uint4), ua = arow4[(ks<<2)+g]
//   B: vvb table [k>>3][col16][k&7], ub = vvb4[((ks<<2)+g)*16 + c]
//   acc[tile] accumulates across k-steps AND chunks (C-in = C-out).
// Init (once, before first barrier): sm rows 210-223 = 0 (read by tile 13);
// vvb col 4 = 1.0 (denominator row), cols 5-15 = 0. No don't-care state.
// ---------------------------------------------------------------------------
__global__ __launch_bounds__(256) void featM_kernel(
    const _Float16* __restrict__ h16, float* __restrict__ Mpart) {
  __shared__ ushort sm[224][136];  // 272B rows = 17 uint4, b128-aligned
  __shared__ ushort vvb[2048];     // [kb(16)][col(16)][j(8)] f16
  const int bh = blockIdx.x >> 1;
  const int half = blockIdx.x & 1;
  const int t = threadIdx.x;
  const bool hiH = t >= 128;
  const int tok = t & 127;
  const uint2* __restrict__ hb = (const uint2*)(h16) + (bh << 10) + (half << 9);

  // One-time init: sm pad rows zero; vvb col4 = 1.0, cols 5-15 = 0.
  for (int i = t; i < 14 * 136; i += 256) sm[210 + i / 136][i % 136] = 0;
  for (int i = t; i < 2048; i += 256)
    vvb[i] = (((i >> 3) & 15) == 4) ? (ushort)0x3C00u : (ushort)0u;

  const int lane = t & 63;
  const int w = t >> 6;
  const int c = lane & 15, g = lane >> 4;
  float4v acc[4] = {};

  for (int ch = 0; ch < 4; ++ch) {
    __syncthreads();  // covers init on ch=0; phase2->phase1 on later chunks
    // phase 1: monomials + vvb cols 0-3 for this chunk's 128 tokens
    {
      union { uint2 u; half4v h; ushort4 us; } uz;
      uz.u = hb[(ch << 7) + tok];
      float z0 = (float)uz.h.x, z1 = (float)uz.h.y;
      float z2 = (float)uz.h.z, z3 = (float)uz.h.w;
      if (!hiH) {
        int base = ((tok >> 3) << 7) + (tok & 7);
        vvb[base + 0] = uz.us.x;       // col 0
        vvb[base + 8] = uz.us.y;       // col 1
        vvb[base + 16] = uz.us.z;      // col 2
        vvb[base + 24] = uz.us.w;      // col 3
      }
      for_each_mono(z0, z1, z2, z3,
                    [&](int mi, float m, int, int, int, int) {
                      if (hiH ? (mi >= 105) : (mi < 105)) {
                        union { _Float16 h; ushort u; } cv;
                        cv.h = (_Float16)m;
                        sm[mi][tok] = cv.u;
                      }
                    });
    }
    __syncthreads();
    // phase 2: 4 row-tiles per wave x 4 k-steps, combine-pattern MFMA
    {
      const uint4* __restrict__ vvb4 = (const uint4*)vvb;
      union U4H { uint4 u; half8v h; };
#pragma unroll
      for (int ks = 0; ks < 4; ++ks) {
        U4H ub;
        ub.u = vvb4[(((ks << 2) + g) << 4) + c];
#pragma unroll
        for (int tl = 0; tl < 4; ++tl) {
          const uint4* arow4 = (const uint4*)&sm[(w << 6) + (tl << 4) + c][0];
          U4H ua;
          ua.u = arow4[(ks << 2) + g];
          acc[tl] =
              __builtin_amdgcn_mfma_f32_16x16x32_f16(ua.h, ub.h, acc[tl], 0, 0, 0);
        }
      }
    }
  }

  // epilogue: C/D row = w*64 + tl*16 + g*4 + reg, col = c
  if (c < 5) {
    float* mp = Mpart + ((bh << 1) + half) * 210 * 5;
#pragma unroll
    for (int tl = 0; tl < 4; ++tl) {
#pragma unroll
      for (int reg = 0; reg < 4; ++reg) {
        int row = (w << 6) + (tl << 4) + (g << 2) + reg;
        if (row < 210) mp[row * 5 + c] = acc[tl][reg];
      }
    }
  }
}

// ---------------------------------------------------------------------------
// K2b (R14 v1 VERBATIM, verified): out_num[q] = (w o m_q) . Mw.
// Block = (bh, q-chunk 256). Prologue reduces the 2 half-partials into LDS
// Mw[210][8]. Main loop: fully-unrolled 210-term contraction; w folds to
// compile-time literals.
// ---------------------------------------------------------------------------
__global__ __launch_bounds__(256) void featC_kernel(
    const _Float16* __restrict__ h16, const float* __restrict__ Mpart,
    uint2* __restrict__ o16u2) {
  __shared__ float Mw[210][8];
  const int bh = blockIdx.x >> 2;
  const int qc = blockIdx.x & 3;
  const int t = threadIdx.x;
  if (t < 210) {
    const float* m0 = Mpart + ((bh << 1) * 210 + t) * 5;
    const float* m1 = m0 + 210 * 5;
#pragma unroll
    for (int c = 0; c < 5; ++c) Mw[t][c] = m0[c] + m1[c];
  }
  __syncthreads();

  const int q = (qc << 8) + t;
  union { uint2 u; half4v h; } uz;
  uz.u = ((const uint2*)h16)[(bh << 10) + q];
  float z0 = (float)uz.h.x, z1 = (float)uz.h.y;
  float z2 = (float)uz.h.z, z3 = (float)uz.h.w;

  float n0 = 0.f, n1 = 0.f, n2 = 0.f, n3 = 0.f, den = 0.f;
  for_each_mono(z0, z1, z2, z3,
                [&](int mi, float m, int a0, int a1, int a2, int a3) {
                  float wm = m * wcoef(a0, a1, a2, a3);  // literal after unroll
                  float4 M4 = *(const float4*)&Mw[mi][0];
                  n0 += wm * M4.x; n1 += wm * M4.y;
                  n2 += wm * M4.z; n3 += wm * M4.w;
                  den += wm * Mw[mi][4];
                });

  float inv = 1.0f / den;
  union { fp16x2 p[2]; uint2 u; } res;
  res.p[0] = __builtin_amdgcn_cvt_pkrtz(n0 * inv, n1 * inv);
  res.p[1] = __builtin_amdgcn_cvt_pkrtz(n2 * inv, n3 * inv);
  int b = bh >> 5, head = bh & 31;
  o16u2[(((b << 10) + q) << 5) + head] = res.u;
}

// ---------------------------------------------------------------------------
// K0: pack W into B-fragment layout wtb[e>>3][col][e&7] (f16).
// ---------------------------------------------------------------------------
__global__ __launch_bounds__(256) void wtb_kernel(
    const float* __restrict__ W, _Float16* __restrict__ wtb) {
  int i = blockIdx.x * 256 + threadIdx.x;  // 16384
  int col = i >> 7, e = i & 127;
  wtb[((e >> 3) << 10) + (col << 3) + (e & 7)] = (_Float16)W[i];
}

// ---------------------------------------------------------------------------
// K3: combine GEMM out[8192][128] = o16 @ W^T via mfma_f32_16x16x32_f16.
// (verified R6-R20: ~3 us)
// ---------------------------------------------------------------------------
__global__ __launch_bounds__(256) void combine_kernel(
    const _Float16* __restrict__ o16, const _Float16* __restrict__ wtb,
    float* __restrict__ out) {
  const int lane = threadIdx.x & 63;
  const int wv = threadIdx.x >> 6;
  const int job = blockIdx.x * 4 + wv;  // 0..4095
  const int rt = job >> 3, ct = job & 7;
  const int c = lane & 15, g = lane >> 4;
  const uint4* a4 = (const uint4*)o16;
  const uint4* b4 = (const uint4*)wtb;
  const int arow = (rt << 4) + c;
  union U4H { uint4 u; half8v h; };
  float4v acc = {};
#pragma unroll
  for (int t = 0; t < 4; ++t) {
    U4H ua, ub;
    ua.u = a4[(arow << 4) + (t << 2) + g];
    ub.u = b4[(((t << 2) + g) << 7) + (ct << 4) + c];
    acc = __builtin_amdgcn_mfma_f32_16x16x32_f16(ua.h, ub.h, acc, 0, 0, 0);
  }
  const int orow = (rt << 4) + (g << 2);
  const int ocol = (ct << 4) + c;
#pragma unroll
  for (int reg = 0; reg < 4; ++reg)
    out[(orow + reg) * 128 + ocol] = acc[reg];
}

extern "C" void kernel_launch(void* const* d_in, const int* in_sizes, int n_in,
                              void* d_out, int out_size, void* d_ws,
                              size_t ws_size, hipStream_t stream) {
  const float* x = (const float*)d_in[0];   // [8,1024,128] f32
  const float* qp = (const float*)d_in[1];  // [1,4] f32
  const float* W = (const float*)d_in[2];   // [128,128] f32
  float* out = (float*)d_out;               // [8,1024,128] f32

  char* ws = (char*)d_ws;
  _Float16* h16 = (_Float16*)ws;                 // [256][1024][4] f16 = 2 MB
  float* Mpart = (float*)(ws + (2 << 20));       // [256][2][210][5] f32 ~2.1MB
  _Float16* o16 = (_Float16*)(ws + (6 << 20));   // [8192][128] f16 = 2 MB
  _Float16* wtb = (_Float16*)(ws + (8 << 20));   // [16][128][8] f16 = 32 KB

  wtb_kernel<<<64, 256, 0, stream>>>(W, wtb);
  qenc_kernel<<<1024, 256, 0, stream>>>((const float4*)x, qp, (uint2*)h16);
  featM_kernel<<<512, 256, 0, stream>>>(h16, Mpart);
  featC_kernel<<<1024, 256, 0, stream>>>(h16, Mpart, (uint2*)o16);
  combine_kernel<<<1024, 256, 0, stream>>>(o16, wtb, out);
}

// Round 22
// 35.248 us; speedup vs baseline: 2.1922x; 1.2618x over previous
//
#include <hip/hip_runtime.h>

// Problem constants: B=8, S=1024, E=128, H=32, DK=4.
constexpr int kS = 1024;
constexpr int NM = 126;  // monomials of degree <=5 in 4 vars: C(9,4)

typedef __fp16 fp16x2 __attribute__((ext_vector_type(2)));
typedef _Float16 half4v __attribute__((ext_vector_type(4)));
typedef _Float16 half8v __attribute__((ext_vector_type(8)));
typedef float float4v __attribute__((ext_vector_type(4)));

// ---------------------------------------------------------------------------
// Feature-map attention (R14-R21 verified at deg-6): P[q,k] = e^{q.k/2}.
// R22: degree 6 -> 5. Truncation err 2*I6(2) ~ 3.2e-3 (was 5e-4); still
// ~2x under the 1.06e-2 threshold after softmax propagation. Basis shrinks
// 210 -> 126, scaling every hot loop by 0.6.
// Deg-5 power coeffs from e^s = I0 + 2*sum I_n(2) T_n(s/2), T6+ dropped:
//   b = {1.0031455, 1.0010453, 0.4860342, 0.1641117, 0.0507286, 0.0097257}
//   (odd terms match deg-6; even terms absorb the removed T6.)
//   M[a][c]  = sum_k m_k[a]*vv_k[c]   (vv = [z,1]; col 4 = denominator)
//   num[q][c] = sum_a m_q[a] * (w_a M[a][c]);  out = num[0..3]/num[4].
// ---------------------------------------------------------------------------

__device__ __forceinline__ float wcoef(int a0, int a1, int a2, int a3) {
  const float b[6] = {1.0031455f, 1.0010453f, 0.4860342f,
                      0.1641117f, 0.0507286f, 0.0097257f};
  const float f[6] = {1.f, 1.f, 2.f, 6.f, 24.f, 120.f};
  const float p2[6] = {1.f, 2.f, 4.f, 8.f, 16.f, 32.f};
  int n = a0 + a1 + a2 + a3;
  return b[n] * f[n] / (p2[n] * f[a0] * f[a1] * f[a2] * f[a3]);
}

// Canonical graded enumeration of the 126 deg<=5 monomials; shared by all
// kernels so slot s <-> monomial s is consistent (MFMA A/B pairing).
template <class F>
__device__ __forceinline__ void for_each_mono(float z0, float z1, float z2,
                                              float z3, F&& f) {
  int idx = 0;
  float p0 = 1.f;
#pragma unroll
  for (int a0 = 0; a0 <= 5; ++a0) {
    float p1 = p0;
#pragma unroll
    for (int a1 = 0; a1 <= 5 - a0; ++a1) {
      float p2 = p1;
#pragma unroll
      for (int a2 = 0; a2 <= 5 - a0 - a1; ++a2) {
        float p3 = p2;
#pragma unroll
        for (int a3 = 0; a3 <= 5 - a0 - a1 - a2; ++a3) {
          f(idx, p3, a0, a1, a2, a3);
          ++idx;
          p3 *= z3;
        }
        p2 *= z2;
      }
      p1 *= z1;
    }
    p0 *= z0;
  }
}

// ---------------------------------------------------------------------------
// K1: quantum encoder (analytic collapse, verified R1-R21).
// ---------------------------------------------------------------------------
__global__ __launch_bounds__(256) void qenc_kernel(
    const float4* __restrict__ x4, const float* __restrict__ qp,
    uint2* __restrict__ h16u) {
  int idx = blockIdx.x * 256 + threadIdx.x;
  float4 a = x4[idx];
  float c0 = cosf(a.x + qp[0]);
  float c1 = cosf(a.y + qp[1]);
  float c2 = cosf(a.z + qp[2]);
  float c3 = cosf(a.w + qp[3]);
  float z1 = c0 * c1;
  float z2 = z1 * c2;
  float z3 = z2 * c3;
  float z0 = c1 * c2 * c3;
  union { half4v h; uint2 u; } z;
  z.h.x = (_Float16)z0;
  z.h.y = (_Float16)z1;
  z.h.z = (_Float16)z2;
  z.h.w = (_Float16)z3;
  int b = idx >> 15;
  int s = (idx >> 5) & (kS - 1);
  int head = idx & 31;
  int bh = b * 32 + head;
  h16u[(bh << 10) + s] = z.u;
}

// ---------------------------------------------------------------------------
// K2a (R21 MFMA structure, 126 rows): M[bh][half][row][c].
// Block = (bh, half of 512 keys), 4 chunks of 128 keys.
// Phase1: 2 threads/token write 63 monomials each into sm[mi][tok].
// Phase2: mfma_f32_16x16x32_f16, combine-pattern fragments; 2 row-tiles/wave
// (128 rows total, rows 126-127 zero-padded at init). acc accumulates across
// k-steps and chunks. vvb col 4 = 1.0 (denominator), cols 5-15 = 0.
// LDS: sm 34.8KB + vvb 4KB -> 4 blocks/CU (was 2 at deg-6).
// ---------------------------------------------------------------------------
__global__ __launch_bounds__(256) void featM_kernel(
    const _Float16* __restrict__ h16, float* __restrict__ Mpart) {
  __shared__ ushort sm[128][136];  // 272B rows = 17 uint4, b128-aligned
  __shared__ ushort vvb[2048];     // [kb(16)][col(16)][j(8)] f16
  const int bh = blockIdx.x >> 1;
  const int half = blockIdx.x & 1;
  const int t = threadIdx.x;
  const bool hiH = t >= 128;
  const int tok = t & 127;
  const uint2* __restrict__ hb = (const uint2*)(h16) + (bh << 10) + (half << 9);

  // One-time init: sm pad rows (126,127) zero; vvb col4 = 1.0, cols 5-15 = 0.
  for (int i = t; i < 2 * 136; i += 256) sm[126 + i / 136][i % 136] = 0;
  for (int i = t; i < 2048; i += 256)
    vvb[i] = (((i >> 3) & 15) == 4) ? (ushort)0x3C00u : (ushort)0u;

  const int lane = t & 63;
  const int w = t >> 6;
  const int c = lane & 15, g = lane >> 4;
  float4v acc[2] = {};

  for (int ch = 0; ch < 4; ++ch) {
    __syncthreads();  // covers init on ch=0; phase2->phase1 on later chunks
    // phase 1: monomials + vvb cols 0-3 for this chunk's 128 tokens
    {
      union { uint2 u; half4v h; ushort4 us; } uz;
      uz.u = hb[(ch << 7) + tok];
      float z0 = (float)uz.h.x, z1 = (float)uz.h.y;
      float z2 = (float)uz.h.z, z3 = (float)uz.h.w;
      if (!hiH) {
        int base = ((tok >> 3) << 7) + (tok & 7);
        vvb[base + 0] = uz.us.x;   // col 0
        vvb[base + 8] = uz.us.y;   // col 1
        vvb[base + 16] = uz.us.z;  // col 2
        vvb[base + 24] = uz.us.w;  // col 3
      }
      for_each_mono(z0, z1, z2, z3,
                    [&](int mi, float m, int, int, int, int) {
                      if (hiH ? (mi >= 63) : (mi < 63)) {
                        union { _Float16 h; ushort u; } cv;
                        cv.h = (_Float16)m;
                        sm[mi][tok] = cv.u;
                      }
                    });
    }
    __syncthreads();
    // phase 2: 2 row-tiles per wave x 4 k-steps, combine-pattern MFMA
    {
      const uint4* __restrict__ vvb4 = (const uint4*)vvb;
      union U4H { uint4 u; half8v h; };
#pragma unroll
      for (int ks = 0; ks < 4; ++ks) {
        U4H ub;
        ub.u = vvb4[(((ks << 2) + g) << 4) + c];
#pragma unroll
        for (int tl = 0; tl < 2; ++tl) {
          const uint4* arow4 = (const uint4*)&sm[(w << 5) + (tl << 4) + c][0];
          U4H ua;
          ua.u = arow4[(ks << 2) + g];
          acc[tl] = __builtin_amdgcn_mfma_f32_16x16x32_f16(ua.h, ub.h,
                                                           acc[tl], 0, 0, 0);
        }
      }
    }
  }

  // epilogue: C/D row = w*32 + tl*16 + g*4 + reg, col = c
  if (c < 5) {
    float* mp = Mpart + ((bh << 1) + half) * NM * 5;
#pragma unroll
    for (int tl = 0; tl < 2; ++tl) {
#pragma unroll
      for (int reg = 0; reg < 4; ++reg) {
        int row = (w << 5) + (tl << 4) + (g << 2) + reg;
        if (row < NM) mp[row * 5 + c] = acc[tl][reg];
      }
    }
  }
}

// ---------------------------------------------------------------------------
// K2b (R14 structure, 126 terms): out_num[q] = (w o m_q) . Mw.
// Block = (bh, q-chunk 256). Prologue reduces the 2 half-partials into LDS
// Mw[126][8]. Main loop: fully-unrolled 126-term contraction; w folds to
// compile-time literals.
// ---------------------------------------------------------------------------
__global__ __launch_bounds__(256) void featC_kernel(
    const _Float16* __restrict__ h16, const float* __restrict__ Mpart,
    uint2* __restrict__ o16u2) {
  __shared__ float Mw[NM][8];
  const int bh = blockIdx.x >> 2;
  const int qc = blockIdx.x & 3;
  const int t = threadIdx.x;
  if (t < NM) {
    const float* m0 = Mpart + ((bh << 1) * NM + t) * 5;
    const float* m1 = m0 + NM * 5;
#pragma unroll
    for (int c = 0; c < 5; ++c) Mw[t][c] = m0[c] + m1[c];
  }
  __syncthreads();

  const int q = (qc << 8) + t;
  union { uint2 u; half4v h; } uz;
  uz.u = ((const uint2*)h16)[(bh << 10) + q];
  float z0 = (float)uz.h.x, z1 = (float)uz.h.y;
  float z2 = (float)uz.h.z, z3 = (float)uz.h.w;

  float n0 = 0.f, n1 = 0.f, n2 = 0.f, n3 = 0.f, den = 0.f;
  for_each_mono(z0, z1, z2, z3,
                [&](int mi, float m, int a0, int a1, int a2, int a3) {
                  float wm = m * wcoef(a0, a1, a2, a3);  // literal after unroll
                  float4 M4 = *(const float4*)&Mw[mi][0];
                  n0 += wm * M4.x; n1 += wm * M4.y;
                  n2 += wm * M4.z; n3 += wm * M4.w;
                  den += wm * Mw[mi][4];
                });

  float inv = 1.0f / den;
  union { fp16x2 p[2]; uint2 u; } res;
  res.p[0] = __builtin_amdgcn_cvt_pkrtz(n0 * inv, n1 * inv);
  res.p[1] = __builtin_amdgcn_cvt_pkrtz(n2 * inv, n3 * inv);
  int b = bh >> 5, head = bh & 31;
  o16u2[(((b << 10) + q) << 5) + head] = res.u;
}

// ---------------------------------------------------------------------------
// K0: pack W into B-fragment layout wtb[e>>3][col][e&7] (f16).
// ---------------------------------------------------------------------------
__global__ __launch_bounds__(256) void wtb_kernel(
    const float* __restrict__ W, _Float16* __restrict__ wtb) {
  int i = blockIdx.x * 256 + threadIdx.x;  // 16384
  int col = i >> 7, e = i & 127;
  wtb[((e >> 3) << 10) + (col << 3) + (e & 7)] = (_Float16)W[i];
}

// ---------------------------------------------------------------------------
// K3: combine GEMM out[8192][128] = o16 @ W^T via mfma_f32_16x16x32_f16.
// (verified R6-R21: ~3 us)
// ---------------------------------------------------------------------------
__global__ __launch_bounds__(256) void combine_kernel(
    const _Float16* __restrict__ o16, const _Float16* __restrict__ wtb,
    float* __restrict__ out) {
  const int lane = threadIdx.x & 63;
  const int wv = threadIdx.x >> 6;
  const int job = blockIdx.x * 4 + wv;  // 0..4095
  const int rt = job >> 3, ct = job & 7;
  const int c = lane & 15, g = lane >> 4;
  const uint4* a4 = (const uint4*)o16;
  const uint4* b4 = (const uint4*)wtb;
  const int arow = (rt << 4) + c;
  union U4H { uint4 u; half8v h; };
  float4v acc = {};
#pragma unroll
  for (int t = 0; t < 4; ++t) {
    U4H ua, ub;
    ua.u = a4[(arow << 4) + (t << 2) + g];
    ub.u = b4[(((t << 2) + g) << 7) + (ct << 4) + c];
    acc = __builtin_amdgcn_mfma_f32_16x16x32_f16(ua.h, ub.h, acc, 0, 0, 0);
  }
  const int orow = (rt << 4) + (g << 2);
  const int ocol = (ct << 4) + c;
#pragma unroll
  for (int reg = 0; reg < 4; ++reg)
    out[(orow + reg) * 128 + ocol] = acc[reg];
}

extern "C" void kernel_launch(void* const* d_in, const int* in_sizes, int n_in,
                              void* d_out, int out_size, void* d_ws,
                              size_t ws_size, hipStream_t stream) {
  const float* x = (const float*)d_in[0];   // [8,1024,128] f32
  const float* qp = (const float*)d_in[1];  // [1,4] f32
  const float* W = (const float*)d_in[2];   // [128,128] f32
  float* out = (float*)d_out;               // [8,1024,128] f32

  char* ws = (char*)d_ws;
  _Float16* h16 = (_Float16*)ws;                 // [256][1024][4] f16 = 2 MB
  float* Mpart = (float*)(ws + (2 << 20));       // [256][2][126][5] f32 ~1.3MB
  _Float16* o16 = (_Float16*)(ws + (6 << 20));   // [8192][128] f16 = 2 MB
  _Float16* wtb = (_Float16*)(ws + (8 << 20));   // [16][128][8] f16 = 32 KB

  wtb_kernel<<<64, 256, 0, stream>>>(W, wtb);
  qenc_kernel<<<1024, 256, 0, stream>>>((const float4*)x, qp, (uint2*)h16);
  featM_kernel<<<512, 256, 0, stream>>>(h16, Mpart);
  featC_kernel<<<1024, 256, 0, stream>>>(h16, Mpart, (uint2*)o16);
  combine_kernel<<<1024, 256, 0, stream>>>(o16, wtb, out);
}

// Round 23
// 32.718 us; speedup vs baseline: 2.3618x; 1.0773x over previous
//
#include <hip/hip_runtime.h>

// Problem constants: B=8, S=1024, E=128, H=32, DK=4.
constexpr int kS = 1024;
constexpr int NM = 126;  // monomials of degree <=5 in 4 vars: C(9,4)

typedef __fp16 fp16x2 __attribute__((ext_vector_type(2)));
typedef _Float16 half4v __attribute__((ext_vector_type(4)));
typedef _Float16 half8v __attribute__((ext_vector_type(8)));
typedef float float4v __attribute__((ext_vector_type(4)));

// ---------------------------------------------------------------------------
// Feature-map attention (verified R14-R22): P[q,k] = e^{q.k/2}, deg-5
// Chebyshev basis (126 monomials).
//   M[a][c]  = sum_k m_k[a]*vv_k[c]   (vv = [z,1]; col 4 = denominator)
//   num[q][c] = sum_a m_q[a] * (w_a M[a][c]);  out = num[0..3]/num[4].
// R23: featC v7 = 2 q-rows/thread with f32 Mw (halves LDS reads per q;
// R17/R20 lesson: NO f16 repack on the scalar path). wtb folded into qenc
// (-1 launch). featM/combine are R21/R22-verbatim.
// ---------------------------------------------------------------------------

__device__ __forceinline__ float wcoef(int a0, int a1, int a2, int a3) {
  const float b[6] = {1.0031455f, 1.0010453f, 0.4860342f,
                      0.1641117f, 0.0507286f, 0.0097257f};
  const float f[6] = {1.f, 1.f, 2.f, 6.f, 24.f, 120.f};
  const float p2[6] = {1.f, 2.f, 4.f, 8.f, 16.f, 32.f};
  int n = a0 + a1 + a2 + a3;
  return b[n] * f[n] / (p2[n] * f[a0] * f[a1] * f[a2] * f[a3]);
}

// Canonical graded enumeration of the 126 deg<=5 monomials; shared by all
// kernels so slot s <-> monomial s is consistent (MFMA A/B pairing).
template <class F>
__device__ __forceinline__ void for_each_mono(float z0, float z1, float z2,
                                              float z3, F&& f) {
  int idx = 0;
  float p0 = 1.f;
#pragma unroll
  for (int a0 = 0; a0 <= 5; ++a0) {
    float p1 = p0;
#pragma unroll
    for (int a1 = 0; a1 <= 5 - a0; ++a1) {
      float p2 = p1;
#pragma unroll
      for (int a2 = 0; a2 <= 5 - a0 - a1; ++a2) {
        float p3 = p2;
#pragma unroll
        for (int a3 = 0; a3 <= 5 - a0 - a1 - a2; ++a3) {
          f(idx, p3, a0, a1, a2, a3);
          ++idx;
          p3 *= z3;
        }
        p2 *= z2;
      }
      p1 *= z1;
    }
    p0 *= z0;
  }
}

// ---------------------------------------------------------------------------
// K1: quantum encoder (analytic collapse, verified R1-R22) + W pack fused
// (blocks < 64 also build wtb[e>>3][col][e&7] = f16(W[col][e])).
// ---------------------------------------------------------------------------
__global__ __launch_bounds__(256) void qenc_kernel(
    const float4* __restrict__ x4, const float* __restrict__ qp,
    uint2* __restrict__ h16u, const float* __restrict__ W,
    _Float16* __restrict__ wtb) {
  int idx = blockIdx.x * 256 + threadIdx.x;
  if (blockIdx.x < 64) {
    int i = idx;  // 0..16383
    int col = i >> 7, e = i & 127;
    wtb[((e >> 3) << 10) + (col << 3) + (e & 7)] = (_Float16)W[i];
  }
  float4 a = x4[idx];
  float c0 = cosf(a.x + qp[0]);
  float c1 = cosf(a.y + qp[1]);
  float c2 = cosf(a.z + qp[2]);
  float c3 = cosf(a.w + qp[3]);
  float z1 = c0 * c1;
  float z2 = z1 * c2;
  float z3 = z2 * c3;
  float z0 = c1 * c2 * c3;
  union { half4v h; uint2 u; } z;
  z.h.x = (_Float16)z0;
  z.h.y = (_Float16)z1;
  z.h.z = (_Float16)z2;
  z.h.w = (_Float16)z3;
  int b = idx >> 15;
  int s = (idx >> 5) & (kS - 1);
  int head = idx & 31;
  int bh = b * 32 + head;
  h16u[(bh << 10) + s] = z.u;
}

// ---------------------------------------------------------------------------
// K2a (R21/R22-verbatim, verified): M[bh][half][row][c] via MFMA phase 2.
// ---------------------------------------------------------------------------
__global__ __launch_bounds__(256) void featM_kernel(
    const _Float16* __restrict__ h16, float* __restrict__ Mpart) {
  __shared__ ushort sm[128][136];  // 272B rows = 17 uint4, b128-aligned
  __shared__ ushort vvb[2048];     // [kb(16)][col(16)][j(8)] f16
  const int bh = blockIdx.x >> 1;
  const int half = blockIdx.x & 1;
  const int t = threadIdx.x;
  const bool hiH = t >= 128;
  const int tok = t & 127;
  const uint2* __restrict__ hb = (const uint2*)(h16) + (bh << 10) + (half << 9);

  // One-time init: sm pad rows (126,127) zero; vvb col4 = 1.0, cols 5-15 = 0.
  for (int i = t; i < 2 * 136; i += 256) sm[126 + i / 136][i % 136] = 0;
  for (int i = t; i < 2048; i += 256)
    vvb[i] = (((i >> 3) & 15) == 4) ? (ushort)0x3C00u : (ushort)0u;

  const int lane = t & 63;
  const int w = t >> 6;
  const int c = lane & 15, g = lane >> 4;
  float4v acc[2] = {};

  for (int ch = 0; ch < 4; ++ch) {
    __syncthreads();  // covers init on ch=0; phase2->phase1 on later chunks
    {
      union { uint2 u; half4v h; ushort4 us; } uz;
      uz.u = hb[(ch << 7) + tok];
      float z0 = (float)uz.h.x, z1 = (float)uz.h.y;
      float z2 = (float)uz.h.z, z3 = (float)uz.h.w;
      if (!hiH) {
        int base = ((tok >> 3) << 7) + (tok & 7);
        vvb[base + 0] = uz.us.x;   // col 0
        vvb[base + 8] = uz.us.y;   // col 1
        vvb[base + 16] = uz.us.z;  // col 2
        vvb[base + 24] = uz.us.w;  // col 3
      }
      for_each_mono(z0, z1, z2, z3,
                    [&](int mi, float m, int, int, int, int) {
                      if (hiH ? (mi >= 63) : (mi < 63)) {
                        union { _Float16 h; ushort u; } cv;
                        cv.h = (_Float16)m;
                        sm[mi][tok] = cv.u;
                      }
                    });
    }
    __syncthreads();
    {
      const uint4* __restrict__ vvb4 = (const uint4*)vvb;
      union U4H { uint4 u; half8v h; };
#pragma unroll
      for (int ks = 0; ks < 4; ++ks) {
        U4H ub;
        ub.u = vvb4[(((ks << 2) + g) << 4) + c];
#pragma unroll
        for (int tl = 0; tl < 2; ++tl) {
          const uint4* arow4 = (const uint4*)&sm[(w << 5) + (tl << 4) + c][0];
          U4H ua;
          ua.u = arow4[(ks << 2) + g];
          acc[tl] = __builtin_amdgcn_mfma_f32_16x16x32_f16(ua.h, ub.h,
                                                           acc[tl], 0, 0, 0);
        }
      }
    }
  }

  if (c < 5) {
    float* mp = Mpart + ((bh << 1) + half) * NM * 5;
#pragma unroll
    for (int tl = 0; tl < 2; ++tl) {
#pragma unroll
      for (int reg = 0; reg < 4; ++reg) {
        int row = (w << 5) + (tl << 4) + (g << 2) + reg;
        if (row < NM) mp[row * 5 + c] = acc[tl][reg];
      }
    }
  }
}

// ---------------------------------------------------------------------------
// K2b v7: out_num[q] = (w o m_q) . Mw, TWO q-rows per thread (q, q+256) so
// each f32 Mw read (float4 + b32, R14-verified form) serves 2 Horner chains.
// Block = (bh, half of 1024 q), grid 512. w folds to literals after unroll.
// ---------------------------------------------------------------------------
__global__ __launch_bounds__(256) void featC_kernel(
    const _Float16* __restrict__ h16, const float* __restrict__ Mpart,
    uint2* __restrict__ o16u2) {
  __shared__ float Mw[NM][8];
  const int bh = blockIdx.x >> 1;
  const int qh = blockIdx.x & 1;
  const int t = threadIdx.x;
  if (t < NM) {
    const float* m0 = Mpart + ((bh << 1) * NM + t) * 5;
    const float* m1 = m0 + NM * 5;
#pragma unroll
    for (int c = 0; c < 5; ++c) Mw[t][c] = m0[c] + m1[c];
  }
  __syncthreads();

  const int q0 = (qh << 9) + t;  // second row: q0 + 256
  const uint2* hz = (const uint2*)h16 + (bh << 10);
  union { uint2 u; half4v h; } ua, ub;
  ua.u = hz[q0];
  ub.u = hz[q0 + 256];
  float xa0 = (float)ua.h.x, xa1 = (float)ua.h.y;
  float xa2 = (float)ua.h.z, xa3 = (float)ua.h.w;
  float xb0 = (float)ub.h.x, xb1 = (float)ub.h.y;
  float xb2 = (float)ub.h.z, xb3 = (float)ub.h.w;

  float nA0 = 0.f, nA1 = 0.f, nA2 = 0.f, nA3 = 0.f, dA = 0.f;
  float nB0 = 0.f, nB1 = 0.f, nB2 = 0.f, nB3 = 0.f, dB = 0.f;

  int idx = 0;
  float pa0 = 1.f, pb0 = 1.f;
#pragma unroll
  for (int a0 = 0; a0 <= 5; ++a0) {
    float pa1 = pa0, pb1 = pb0;
#pragma unroll
    for (int a1 = 0; a1 <= 5 - a0; ++a1) {
      float pa2 = pa1, pb2 = pb1;
#pragma unroll
      for (int a2 = 0; a2 <= 5 - a0 - a1; ++a2) {
        float pa3 = pa2, pb3 = pb2;
#pragma unroll
        for (int a3 = 0; a3 <= 5 - a0 - a1 - a2; ++a3) {
          float w = wcoef(a0, a1, a2, a3);  // literal after unroll
          float wa = pa3 * w, wb = pb3 * w;
          float4 M4 = *(const float4*)&Mw[idx][0];
          float M5 = Mw[idx][4];
          nA0 += wa * M4.x; nA1 += wa * M4.y;
          nA2 += wa * M4.z; nA3 += wa * M4.w;
          dA += wa * M5;
          nB0 += wb * M4.x; nB1 += wb * M4.y;
          nB2 += wb * M4.z; nB3 += wb * M4.w;
          dB += wb * M5;
          ++idx;
          pa3 *= xa3; pb3 *= xb3;
        }
        pa2 *= xa2; pb2 *= xb2;
      }
      pa1 *= xa1; pb1 *= xb1;
    }
    pa0 *= xa0; pb0 *= xb0;
  }

  const int b_ = bh >> 5, head = bh & 31;
  {
    float inv = 1.0f / dA;
    union { fp16x2 p[2]; uint2 u; } res;
    res.p[0] = __builtin_amdgcn_cvt_pkrtz(nA0 * inv, nA1 * inv);
    res.p[1] = __builtin_amdgcn_cvt_pkrtz(nA2 * inv, nA3 * inv);
    o16u2[(((b_ << 10) + q0) << 5) + head] = res.u;
  }
  {
    float inv = 1.0f / dB;
    union { fp16x2 p[2]; uint2 u; } res;
    res.p[0] = __builtin_amdgcn_cvt_pkrtz(nB0 * inv, nB1 * inv);
    res.p[1] = __builtin_amdgcn_cvt_pkrtz(nB2 * inv, nB3 * inv);
    o16u2[(((b_ << 10) + q0 + 256) << 5) + head] = res.u;
  }
}

// ---------------------------------------------------------------------------
// K3: combine GEMM out[8192][128] = o16 @ W^T via mfma_f32_16x16x32_f16.
// (verified R6-R22: ~3 us)
// ---------------------------------------------------------------------------
__global__ __launch_bounds__(256) void combine_kernel(
    const _Float16* __restrict__ o16, const _Float16* __restrict__ wtb,
    float* __restrict__ out) {
  const int lane = threadIdx.x & 63;
  const int wv = threadIdx.x >> 6;
  const int job = blockIdx.x * 4 + wv;  // 0..4095
  const int rt = job >> 3, ct = job & 7;
  const int c = lane & 15, g = lane >> 4;
  const uint4* a4 = (const uint4*)o16;
  const uint4* b4 = (const uint4*)wtb;
  const int arow = (rt << 4) + c;
  union U4H { uint4 u; half8v h; };
  float4v acc = {};
#pragma unroll
  for (int t = 0; t < 4; ++t) {
    U4H ua, ub;
    ua.u = a4[(arow << 4) + (t << 2) + g];
    ub.u = b4[(((t << 2) + g) << 7) + (ct << 4) + c];
    acc = __builtin_amdgcn_mfma_f32_16x16x32_f16(ua.h, ub.h, acc, 0, 0, 0);
  }
  const int orow = (rt << 4) + (g << 2);
  const int ocol = (ct << 4) + c;
#pragma unroll
  for (int reg = 0; reg < 4; ++reg)
    out[(orow + reg) * 128 + ocol] = acc[reg];
}

extern "C" void kernel_launch(void* const* d_in, const int* in_sizes, int n_in,
                              void* d_out, int out_size, void* d_ws,
                              size_t ws_size, hipStream_t stream) {
  const float* x = (const float*)d_in[0];   // [8,1024,128] f32
  const float* qp = (const float*)d_in[1];  // [1,4] f32
  const float* W = (const float*)d_in[2];   // [128,128] f32
  float* out = (float*)d_out;               // [8,1024,128] f32

  char* ws = (char*)d_ws;
  _Float16* h16 = (_Float16*)ws;                 // [256][1024][4] f16 = 2 MB
  float* Mpart = (float*)(ws + (2 << 20));       // [256][2][126][5] f32 ~1.3MB
  _Float16* o16 = (_Float16*)(ws + (6 << 20));   // [8192][128] f16 = 2 MB
  _Float16* wtb = (_Float16*)(ws + (8 << 20));   // [16][128][8] f16 = 32 KB

  qenc_kernel<<<1024, 256, 0, stream>>>((const float4*)x, qp, (uint2*)h16, W,
                                        wtb);
  featM_kernel<<<512, 256, 0, stream>>>(h16, Mpart);
  featC_kernel<<<512, 256, 0, stream>>>(h16, Mpart, (uint2*)o16);
  combine_kernel<<<1024, 256, 0, stream>>>(o16, wtb, out);
}

// Round 24
// 31.377 us; speedup vs baseline: 2.4627x; 1.0427x over previous
//
#include <hip/hip_runtime.h>

// Problem constants: B=8, S=1024, E=128, H=32, DK=4.
constexpr int kS = 1024;
constexpr int NM = 126;  // monomials of degree <=5 in 4 vars: C(9,4)

typedef __fp16 fp16x2 __attribute__((ext_vector_type(2)));
typedef _Float16 half4v __attribute__((ext_vector_type(4)));
typedef _Float16 half8v __attribute__((ext_vector_type(8)));
typedef float float4v __attribute__((ext_vector_type(4)));

// ---------------------------------------------------------------------------
// Feature-map attention (verified R14-R22): P[q,k] = e^{q.k/2}, deg-5
// Chebyshev basis (126 monomials).
//   M[a][c]  = sum_k m_k[a]*vv_k[c]   (vv = [z,1]; col 4 = denominator)
//   num[q][c] = sum_a m_q[a] * (w_a M[a][c]);  out = num[0..3]/num[4].
// R23: featC v7 = 2 q-rows/thread with f32 Mw (halves LDS reads per q;
// R17/R20 lesson: NO f16 repack on the scalar path). wtb folded into qenc
// (-1 launch). featM/combine are R21/R22-verbatim.
// ---------------------------------------------------------------------------

__device__ __forceinline__ float wcoef(int a0, int a1, int a2, int a3) {
  const float b[6] = {1.0031455f, 1.0010453f, 0.4860342f,
                      0.1641117f, 0.0507286f, 0.0097257f};
  const float f[6] = {1.f, 1.f, 2.f, 6.f, 24.f, 120.f};
  const float p2[6] = {1.f, 2.f, 4.f, 8.f, 16.f, 32.f};
  int n = a0 + a1 + a2 + a3;
  return b[n] * f[n] / (p2[n] * f[a0] * f[a1] * f[a2] * f[a3]);
}

// Canonical graded enumeration of the 126 deg<=5 monomials; shared by all
// kernels so slot s <-> monomial s is consistent (MFMA A/B pairing).
template <class F>
__device__ __forceinline__ void for_each_mono(float z0, float z1, float z2,
                                              float z3, F&& f) {
  int idx = 0;
  float p0 = 1.f;
#pragma unroll
  for (int a0 = 0; a0 <= 5; ++a0) {
    float p1 = p0;
#pragma unroll
    for (int a1 = 0; a1 <= 5 - a0; ++a1) {
      float p2 = p1;
#pragma unroll
      for (int a2 = 0; a2 <= 5 - a0 - a1; ++a2) {
        float p3 = p2;
#pragma unroll
        for (int a3 = 0; a3 <= 5 - a0 - a1 - a2; ++a3) {
          f(idx, p3, a0, a1, a2, a3);
          ++idx;
          p3 *= z3;
        }
        p2 *= z2;
      }
      p1 *= z1;
    }
    p0 *= z0;
  }
}

// ---------------------------------------------------------------------------
// K1: quantum encoder (analytic collapse, verified R1-R22) + W pack fused
// (blocks < 64 also build wtb[e>>3][col][e&7] = f16(W[col][e])).
// ---------------------------------------------------------------------------
__global__ __launch_bounds__(256) void qenc_kernel(
    const float4* __restrict__ x4, const float* __restrict__ qp,
    uint2* __restrict__ h16u, const float* __restrict__ W,
    _Float16* __restrict__ wtb) {
  int idx = blockIdx.x * 256 + threadIdx.x;
  if (blockIdx.x < 64) {
    int i = idx;  // 0..16383
    int col = i >> 7, e = i & 127;
    wtb[((e >> 3) << 10) + (col << 3) + (e & 7)] = (_Float16)W[i];
  }
  float4 a = x4[idx];
  float c0 = cosf(a.x + qp[0]);
  float c1 = cosf(a.y + qp[1]);
  float c2 = cosf(a.z + qp[2]);
  float c3 = cosf(a.w + qp[3]);
  float z1 = c0 * c1;
  float z2 = z1 * c2;
  float z3 = z2 * c3;
  float z0 = c1 * c2 * c3;
  union { half4v h; uint2 u; } z;
  z.h.x = (_Float16)z0;
  z.h.y = (_Float16)z1;
  z.h.z = (_Float16)z2;
  z.h.w = (_Float16)z3;
  int b = idx >> 15;
  int s = (idx >> 5) & (kS - 1);
  int head = idx & 31;
  int bh = b * 32 + head;
  h16u[(bh << 10) + s] = z.u;
}

// ---------------------------------------------------------------------------
// K2a (R21/R22-verbatim, verified): M[bh][half][row][c] via MFMA phase 2.
// ---------------------------------------------------------------------------
__global__ __launch_bounds__(256) void featM_kernel(
    const _Float16* __restrict__ h16, float* __restrict__ Mpart) {
  __shared__ ushort sm[128][136];  // 272B rows = 17 uint4, b128-aligned
  __shared__ ushort vvb[2048];     // [kb(16)][col(16)][j(8)] f16
  const int bh = blockIdx.x >> 1;
  const int half = blockIdx.x & 1;
  const int t = threadIdx.x;
  const bool hiH = t >= 128;
  const int tok = t & 127;
  const uint2* __restrict__ hb = (const uint2*)(h16) + (bh << 10) + (half << 9);

  // One-time init: sm pad rows (126,127) zero; vvb col4 = 1.0, cols 5-15 = 0.
  for (int i = t; i < 2 * 136; i += 256) sm[126 + i / 136][i % 136] = 0;
  for (int i = t; i < 2048; i += 256)
    vvb[i] = (((i >> 3) & 15) == 4) ? (ushort)0x3C00u : (ushort)0u;

  const int lane = t & 63;
  const int w = t >> 6;
  const int c = lane & 15, g = lane >> 4;
  float4v acc[2] = {};

  for (int ch = 0; ch < 4; ++ch) {
    __syncthreads();  // covers init on ch=0; phase2->phase1 on later chunks
    {
      union { uint2 u; half4v h; ushort4 us; } uz;
      uz.u = hb[(ch << 7) + tok];
      float z0 = (float)uz.h.x, z1 = (float)uz.h.y;
      float z2 = (float)uz.h.z, z3 = (float)uz.h.w;
      if (!hiH) {
        int base = ((tok >> 3) << 7) + (tok & 7);
        vvb[base + 0] = uz.us.x;   // col 0
        vvb[base + 8] = uz.us.y;   // col 1
        vvb[base + 16] = uz.us.z;  // col 2
        vvb[base + 24] = uz.us.w;  // col 3
      }
      for_each_mono(z0, z1, z2, z3,
                    [&](int mi, float m, int, int, int, int) {
                      if (hiH ? (mi >= 63) : (mi < 63)) {
                        union { _Float16 h; ushort u; } cv;
                        cv.h = (_Float16)m;
                        sm[mi][tok] = cv.u;
                      }
                    });
    }
    __syncthreads();
    {
      const uint4* __restrict__ vvb4 = (const uint4*)vvb;
      union U4H { uint4 u; half8v h; };
#pragma unroll
      for (int ks = 0; ks < 4; ++ks) {
        U4H ub;
        ub.u = vvb4[(((ks << 2) + g) << 4) + c];
#pragma unroll
        for (int tl = 0; tl < 2; ++tl) {
          const uint4* arow4 = (const uint4*)&sm[(w << 5) + (tl << 4) + c][0];
          U4H ua;
          ua.u = arow4[(ks << 2) + g];
          acc[tl] = __builtin_amdgcn_mfma_f32_16x16x32_f16(ua.h, ub.h,
                                                           acc[tl], 0, 0, 0);
        }
      }
    }
  }

  if (c < 5) {
    float* mp = Mpart + ((bh << 1) + half) * NM * 5;
#pragma unroll
    for (int tl = 0; tl < 2; ++tl) {
#pragma unroll
      for (int reg = 0; reg < 4; ++reg) {
        int row = (w << 5) + (tl << 4) + (g << 2) + reg;
        if (row < NM) mp[row * 5 + c] = acc[tl][reg];
      }
    }
  }
}

// ---------------------------------------------------------------------------
// K2b v7: out_num[q] = (w o m_q) . Mw, TWO q-rows per thread (q, q+256) so
// each f32 Mw read (float4 + b32, R14-verified form) serves 2 Horner chains.
// Block = (bh, half of 1024 q), grid 512. w folds to literals after unroll.
// ---------------------------------------------------------------------------
__global__ __launch_bounds__(256) void featC_kernel(
    const _Float16* __restrict__ h16, const float* __restrict__ Mpart,
    uint2* __restrict__ o16u2) {
  __shared__ float Mw[NM][8];
  const int bh = blockIdx.x >> 1;
  const int qh = blockIdx.x & 1;
  const int t = threadIdx.x;
  if (t < NM) {
    const float* m0 = Mpart + ((bh << 1) * NM + t) * 5;
    const float* m1 = m0 + NM * 5;
#pragma unroll
    for (int c = 0; c < 5; ++c) Mw[t][c] = m0[c] + m1[c];
  }
  __syncthreads();

  const int q0 = (qh << 9) + t;  // second row: q0 + 256
  const uint2* hz = (const uint2*)h16 + (bh << 10);
  union { uint2 u; half4v h; } ua, ub;
  ua.u = hz[q0];
  ub.u = hz[q0 + 256];
  float xa0 = (float)ua.h.x, xa1 = (float)ua.h.y;
  float xa2 = (float)ua.h.z, xa3 = (float)ua.h.w;
  float xb0 = (float)ub.h.x, xb1 = (float)ub.h.y;
  float xb2 = (float)ub.h.z, xb3 = (float)ub.h.w;

  float nA0 = 0.f, nA1 = 0.f, nA2 = 0.f, nA3 = 0.f, dA = 0.f;
  float nB0 = 0.f, nB1 = 0.f, nB2 = 0.f, nB3 = 0.f, dB = 0.f;

  int idx = 0;
  float pa0 = 1.f, pb0 = 1.f;
#pragma unroll
  for (int a0 = 0; a0 <= 5; ++a0) {
    float pa1 = pa0, pb1 = pb0;
#pragma unroll
    for (int a1 = 0; a1 <= 5 - a0; ++a1) {
      float pa2 = pa1, pb2 = pb1;
#pragma unroll
      for (int a2 = 0; a2 <= 5 - a0 - a1; ++a2) {
        float pa3 = pa2, pb3 = pb2;
#pragma unroll
        for (int a3 = 0; a3 <= 5 - a0 - a1 - a2; ++a3) {
          float w = wcoef(a0, a1, a2, a3);  // literal after unroll
          float wa = pa3 * w, wb = pb3 * w;
          float4 M4 = *(const float4*)&Mw[idx][0];
          float M5 = Mw[idx][4];
          nA0 += wa * M4.x; nA1 += wa * M4.y;
          nA2 += wa * M4.z; nA3 += wa * M4.w;
          dA += wa * M5;
          nB0 += wb * M4.x; nB1 += wb * M4.y;
          nB2 += wb * M4.z; nB3 += wb * M4.w;
          dB += wb * M5;
          ++idx;
          pa3 *= xa3; pb3 *= xb3;
        }
        pa2 *= xa2; pb2 *= xb2;
      }
      pa1 *= xa1; pb1 *= xb1;
    }
    pa0 *= xa0; pb0 *= xb0;
  }

  const int b_ = bh >> 5, head = bh & 31;
  {
    float inv = 1.0f / dA;
    union { fp16x2 p[2]; uint2 u; } res;
    res.p[0] = __builtin_amdgcn_cvt_pkrtz(nA0 * inv, nA1 * inv);
    res.p[1] = __builtin_amdgcn_cvt_pkrtz(nA2 * inv, nA3 * inv);
    o16u2[(((b_ << 10) + q0) << 5) + head] = res.u;
  }
  {
    float inv = 1.0f / dB;
    union { fp16x2 p[2]; uint2 u; } res;
    res.p[0] = __builtin_amdgcn_cvt_pkrtz(nB0 * inv, nB1 * inv);
    res.p[1] = __builtin_amdgcn_cvt_pkrtz(nB2 * inv, nB3 * inv);
    o16u2[(((b_ << 10) + q0 + 256) << 5) + head] = res.u;
  }
}

// ---------------------------------------------------------------------------
// K3: combine GEMM out[8192][128] = o16 @ W^T via mfma_f32_16x16x32_f16.
// (verified R6-R22: ~3 us)
// ---------------------------------------------------------------------------
__global__ __launch_bounds__(256) void combine_kernel(
    const _Float16* __restrict__ o16, const _Float16* __restrict__ wtb,
    float* __restrict__ out) {
  const int lane = threadIdx.x & 63;
  const int wv = threadIdx.x >> 6;
  const int job = blockIdx.x * 4 + wv;  // 0..4095
  const int rt = job >> 3, ct = job & 7;
  const int c = lane & 15, g = lane >> 4;
  const uint4* a4 = (const uint4*)o16;
  const uint4* b4 = (const uint4*)wtb;
  const int arow = (rt << 4) + c;
  union U4H { uint4 u; half8v h; };
  float4v acc = {};
#pragma unroll
  for (int t = 0; t < 4; ++t) {
    U4H ua, ub;
    ua.u = a4[(arow << 4) + (t << 2) + g];
    ub.u = b4[(((t << 2) + g) << 7) + (ct << 4) + c];
    acc = __builtin_amdgcn_mfma_f32_16x16x32_f16(ua.h, ub.h, acc, 0, 0, 0);
  }
  const int orow = (rt << 4) + (g << 2);
  const int ocol = (ct << 4) + c;
#pragma unroll
  for (int reg = 0; reg < 4; ++reg)
    out[(orow + reg) * 128 + ocol] = acc[reg];
}

extern "C" void kernel_launch(void* const* d_in, const int* in_sizes, int n_in,
                              void* d_out, int out_size, void* d_ws,
                              size_t ws_size, hipStream_t stream) {
  const float* x = (const float*)d_in[0];   // [8,1024,128] f32
  const float* qp = (const float*)d_in[1];  // [1,4] f32
  const float* W = (const float*)d_in[2];   // [128,128] f32
  float* out = (float*)d_out;               // [8,1024,128] f32

  char* ws = (char*)d_ws;
  _Float16* h16 = (_Float16*)ws;                 // [256][1024][4] f16 = 2 MB
  float* Mpart = (float*)(ws + (2 << 20));       // [256][2][126][5] f32 ~1.3MB
  _Float16* o16 = (_Float16*)(ws + (6 << 20));   // [8192][128] f16 = 2 MB
  _Float16* wtb = (_Float16*)(ws + (8 << 20));   // [16][128][8] f16 = 32 KB

  qenc_kernel<<<1024, 256, 0, stream>>>((const float4*)x, qp, (uint2*)h16, W,
                                        wtb);
  featM_kernel<<<512, 256, 0, stream>>>(h16, Mpart);
  featC_kernel<<<512, 256, 0, stream>>>(h16, Mpart, (uint2*)o16);
  combine_kernel<<<1024, 256, 0, stream>>>(o16, wtb, out);
}